// Round 1
// baseline (3705.033 us; speedup 1.0000x reference)
//
#include <hip/hip_runtime.h>
#include <hip/hip_bf16.h>

typedef unsigned short u16;

#define NN 8192
#define SSAMP 1024
#define KK 32
#define NT_F 524288.0f
#define EPSV 1e-5f

// ---------------------------------------------------------------------------
// FPS: one block per batch, 256 threads, 32 points/thread in registers.
// Exact replication of reference: dist = (dx*dx + dy*dy) + dz*dz (rn, no fma),
// running min, argmax with first-occurrence (lowest index) tie-break.
// ---------------------------------------------------------------------------
__global__ __launch_bounds__(256, 1) void fps_kernel(const float* __restrict__ xyz,
                                                     float* __restrict__ newxyz) {
  const int b = blockIdx.x, t = threadIdx.x;
  const float* base = xyz + (size_t)b * NN * 3;
  float X[32], Y[32], Z[32], D[32];
#pragma unroll
  for (int j = 0; j < 32; j++) {
    int p = j * 256 + t;
    X[j] = base[p * 3 + 0];
    Y[j] = base[p * 3 + 1];
    Z[j] = base[p * 3 + 2];
    D[j] = 1e10f;
  }
  __shared__ float rv[4];
  __shared__ int ri[4];
  int cur = 0;
  for (int it = 0; it < SSAMP; it++) {
    float cx = base[cur * 3 + 0];
    float cy = base[cur * 3 + 1];
    float cz = base[cur * 3 + 2];
    if (t == 0) {
      float* o = newxyz + ((size_t)b * SSAMP + it) * 3;
      o[0] = cx; o[1] = cy; o[2] = cz;
    }
    float best = -1.0f;
    int bi = 0;
#pragma unroll
    for (int j = 0; j < 32; j++) {
      float dx = __fsub_rn(X[j], cx);
      float dy = __fsub_rn(Y[j], cy);
      float dz = __fsub_rn(Z[j], cz);
      float d = __fadd_rn(__fadd_rn(__fmul_rn(dx, dx), __fmul_rn(dy, dy)), __fmul_rn(dz, dz));
      float dm = fminf(D[j], d);
      D[j] = dm;
      bool g = dm > best;
      best = g ? dm : best;
      bi = g ? (j * 256 + t) : bi;
    }
#pragma unroll
    for (int off = 1; off < 64; off <<= 1) {
      float ov = __shfl_xor(best, off);
      int oi = __shfl_xor(bi, off);
      if (ov > best || (ov == best && oi < bi)) { best = ov; bi = oi; }
    }
    __syncthreads();  // protect rv/ri reads of previous iteration
    if ((t & 63) == 0) { rv[t >> 6] = best; ri[t >> 6] = bi; }
    __syncthreads();
    float bv = rv[0];
    int bj = ri[0];
#pragma unroll
    for (int w = 1; w < 4; w++) {
      float v = rv[w]; int iw = ri[w];
      if (v > bv || (v == bv && iw < bj)) { bv = v; bj = iw; }
    }
    cur = bj;
  }
}

// ---------------------------------------------------------------------------
// Ball query: one thread per centroid; ascending-index scan, first 32 with
// d <= r^2 (exact rn arithmetic), pad with first hit.
// ---------------------------------------------------------------------------
__global__ __launch_bounds__(256) void ballq_kernel(const float* __restrict__ xyz,
                                                    const float* __restrict__ newxyz,
                                                    int* __restrict__ ballidx) {
  int gi = blockIdx.x * 256 + threadIdx.x;  // 0..16383
  int b = gi >> 10;
  const float* base = xyz + (size_t)b * NN * 3;
  float cx = newxyz[gi * 3 + 0];
  float cy = newxyz[gi * 3 + 1];
  float cz = newxyz[gi * 3 + 2];
  int* op = ballidx + (size_t)gi * KK;
  int cnt = 0, first = 0;
  for (int p = 0; p < NN; p++) {
    float dx = __fsub_rn(cx, base[p * 3 + 0]);
    float dy = __fsub_rn(cy, base[p * 3 + 1]);
    float dz = __fsub_rn(cz, base[p * 3 + 2]);
    float d = __fadd_rn(__fadd_rn(__fmul_rn(dx, dx), __fmul_rn(dy, dy)), __fmul_rn(dz, dz));
    if (d <= 0.04f) {
      if (cnt == 0) first = p;
      op[cnt] = p;
      cnt++;
      if (cnt == KK) break;
    }
  }
  for (int q = cnt; q < KK; q++) op[q] = first;
}

// ---------------------------------------------------------------------------
// Shared helpers for the conv/BN pipeline
// ---------------------------------------------------------------------------
__device__ __forceinline__ void stage_W(const float* __restrict__ w, float* Ws, int K, int O, int t) {
  for (int i2 = t; i2 < K * O; i2 += 256) {
    int c = i2 / O, o = i2 % O;
    Ws[i2] = w[o * K + c];  // Ws[c*O + o] = w[o][c]
  }
}

// stage A tile (64 positions x 64 ch) from bf16 Y with BN(scale,shift)+relu
__device__ __forceinline__ void stage_A_bn(const u16* __restrict__ Yin, int pbase, int t,
                                           float* As, const float* sS, const float* sT) {
  int r = t >> 2, q = t & 3;
  const ushort4* yr = (const ushort4*)(Yin + ((size_t)(pbase + r)) * 64);
#pragma unroll
  for (int l = 0; l < 4; l++) {
    ushort4 u = yr[q * 4 + l];
    int c = q * 16 + l * 4;
    union { ushort4 u4; __hip_bfloat16 h[4]; } pk;
    pk.u4 = u;
#pragma unroll
    for (int m2 = 0; m2 < 4; m2++) {
      float f = __bfloat162float(pk.h[m2]);
      f = fmaf(f, sS[c + m2], sT[c + m2]);
      As[(c + m2) * 64 + r] = fmaxf(f, 0.f);
    }
  }
}

// ---------------------------------------------------------------------------
// GEMM1: gather(points,xyz_norm) -> conv1(67->64) + bias, store Y1 bf16, stats
// ---------------------------------------------------------------------------
__global__ __launch_bounds__(256) void gemm1_kernel(const float* __restrict__ xyz,
                                                    const float* __restrict__ pts,
                                                    const float* __restrict__ w1,
                                                    const float* __restrict__ b1,
                                                    const float* __restrict__ newxyz,
                                                    const int* __restrict__ ballidx,
                                                    u16* __restrict__ Y1,
                                                    float* __restrict__ stats) {
  __shared__ __align__(16) float As[67 * 64];
  __shared__ __align__(16) float Ws[67 * 64];
  __shared__ int sidx[64];
  __shared__ float snx[6];
  __shared__ float ssum[64], ssq[64];
  const int t = threadIdx.x, blk = blockIdx.x;
  const int pbase = blk * 64;
  const int g0 = pbase >> 5;
  const int b = g0 >> 10;
  if (t < 64) { sidx[t] = ballidx[pbase + t]; ssum[t] = 0.f; ssq[t] = 0.f; }
  if (t < 6) snx[t] = newxyz[(size_t)g0 * 3 + t];
  stage_W(w1, Ws, 67, 64, t);
  __syncthreads();
  {
    int r = t >> 2, q = t & 3;
    const float4* prow = (const float4*)(pts + ((size_t)b * NN + sidx[r]) * 64);
#pragma unroll
    for (int l = 0; l < 4; l++) {
      float4 v = prow[q * 4 + l];
      int c = 3 + q * 16 + l * 4;
      As[(c + 0) * 64 + r] = v.x;
      As[(c + 1) * 64 + r] = v.y;
      As[(c + 2) * 64 + r] = v.z;
      As[(c + 3) * 64 + r] = v.w;
    }
  }
  if (t < 64) {
    const float* xp = xyz + ((size_t)b * NN + sidx[t]) * 3;
    int g = t >> 5;
    As[0 * 64 + t] = xp[0] - snx[g * 3 + 0];
    As[1 * 64 + t] = xp[1] - snx[g * 3 + 1];
    As[2 * 64 + t] = xp[2] - snx[g * 3 + 2];
  }
  __syncthreads();
  const int i = t & 15, j = t >> 4;
  float acc[4][4];
#pragma unroll
  for (int a = 0; a < 4; a++)
#pragma unroll
    for (int c2 = 0; c2 < 4; c2++) acc[a][c2] = 0.f;
#pragma unroll 4
  for (int c = 0; c < 67; c++) {
    float4 a4 = *(const float4*)&As[c * 64 + i * 4];
    float4 w4 = *(const float4*)&Ws[c * 64 + j * 4];
    float av[4] = {a4.x, a4.y, a4.z, a4.w};
    float wv[4] = {w4.x, w4.y, w4.z, w4.w};
#pragma unroll
    for (int ii = 0; ii < 4; ii++)
#pragma unroll
      for (int jj = 0; jj < 4; jj++) acc[ii][jj] = fmaf(av[ii], wv[jj], acc[ii][jj]);
  }
  float bl[4];
#pragma unroll
  for (int jj = 0; jj < 4; jj++) bl[jj] = b1[j * 4 + jj];
#pragma unroll
  for (int ii = 0; ii < 4; ii++) {
    union { ushort4 u4; __hip_bfloat16 h[4]; } pk;
#pragma unroll
    for (int jj = 0; jj < 4; jj++) {
      float y = acc[ii][jj] + bl[jj];
      acc[ii][jj] = y;
      pk.h[jj] = __float2bfloat16(y);
    }
    *(ushort4*)&Y1[((size_t)(pbase + i * 4 + ii)) * 64 + j * 4] = pk.u4;
  }
#pragma unroll
  for (int jj = 0; jj < 4; jj++) {
    float s = 0.f, q2 = 0.f;
#pragma unroll
    for (int ii = 0; ii < 4; ii++) { float v = acc[ii][jj]; s += v; q2 += v * v; }
    atomicAdd(&ssum[j * 4 + jj], s);
    atomicAdd(&ssq[j * 4 + jj], q2);
  }
  __syncthreads();
  if (t < 64) atomicAdd(&stats[t], ssum[t]);
  else if (t < 128) atomicAdd(&stats[64 + (t - 64)], ssq[t - 64]);
}

// ---------------------------------------------------------------------------
// GEMM2: bn1+relu(Y1) -> conv2(64->64) + bias, store Y2 bf16, stats2
// ---------------------------------------------------------------------------
__global__ __launch_bounds__(256) void gemm2_kernel(const u16* __restrict__ Y1,
                                                    const float* __restrict__ w2,
                                                    const float* __restrict__ b2,
                                                    const float* __restrict__ g1,
                                                    const float* __restrict__ be1,
                                                    float* __restrict__ stats,
                                                    u16* __restrict__ Y2) {
  __shared__ __align__(16) float As[64 * 64];
  __shared__ __align__(16) float Ws[64 * 64];
  __shared__ float sS[64], sT[64];
  __shared__ float ssum[64], ssq[64];
  const int t = threadIdx.x, blk = blockIdx.x;
  const int pbase = blk * 64;
  if (t < 64) {
    float mean = stats[t] * (1.0f / NT_F);
    float var = stats[64 + t] * (1.0f / NT_F) - mean * mean;
    float s = g1[t] * rsqrtf(var + EPSV);
    sS[t] = s;
    sT[t] = be1[t] - mean * s;
    ssum[t] = 0.f; ssq[t] = 0.f;
  }
  stage_W(w2, Ws, 64, 64, t);
  __syncthreads();
  stage_A_bn(Y1, pbase, t, As, sS, sT);
  __syncthreads();
  const int i = t & 15, j = t >> 4;
  float acc[4][4];
#pragma unroll
  for (int a = 0; a < 4; a++)
#pragma unroll
    for (int c2 = 0; c2 < 4; c2++) acc[a][c2] = 0.f;
#pragma unroll 4
  for (int c = 0; c < 64; c++) {
    float4 a4 = *(const float4*)&As[c * 64 + i * 4];
    float4 w4 = *(const float4*)&Ws[c * 64 + j * 4];
    float av[4] = {a4.x, a4.y, a4.z, a4.w};
    float wv[4] = {w4.x, w4.y, w4.z, w4.w};
#pragma unroll
    for (int ii = 0; ii < 4; ii++)
#pragma unroll
      for (int jj = 0; jj < 4; jj++) acc[ii][jj] = fmaf(av[ii], wv[jj], acc[ii][jj]);
  }
  float bl[4];
#pragma unroll
  for (int jj = 0; jj < 4; jj++) bl[jj] = b2[j * 4 + jj];
#pragma unroll
  for (int ii = 0; ii < 4; ii++) {
    union { ushort4 u4; __hip_bfloat16 h[4]; } pk;
#pragma unroll
    for (int jj = 0; jj < 4; jj++) {
      float y = acc[ii][jj] + bl[jj];
      acc[ii][jj] = y;
      pk.h[jj] = __float2bfloat16(y);
    }
    *(ushort4*)&Y2[((size_t)(pbase + i * 4 + ii)) * 64 + j * 4] = pk.u4;
  }
#pragma unroll
  for (int jj = 0; jj < 4; jj++) {
    float s = 0.f, q2 = 0.f;
#pragma unroll
    for (int ii = 0; ii < 4; ii++) { float v = acc[ii][jj]; s += v; q2 += v * v; }
    atomicAdd(&ssum[j * 4 + jj], s);
    atomicAdd(&ssq[j * 4 + jj], q2);
  }
  __syncthreads();
  if (t < 64) atomicAdd(&stats[128 + t], ssum[t]);
  else if (t < 128) atomicAdd(&stats[192 + (t - 64)], ssq[t - 64]);
}

// conv3 inner loop shared by stats and maxout kernels
__device__ __forceinline__ void conv3_compute(const float* As, const float* Ws, int i, int ob,
                                              float acc[4][8]) {
#pragma unroll 4
  for (int c = 0; c < 64; c++) {
    float4 a4 = *(const float4*)&As[c * 64 + i * 4];
    float4 w0 = *(const float4*)&Ws[c * 128 + ob];
    float4 w1v = *(const float4*)&Ws[c * 128 + ob + 4];
    float av[4] = {a4.x, a4.y, a4.z, a4.w};
    float wv[8] = {w0.x, w0.y, w0.z, w0.w, w1v.x, w1v.y, w1v.z, w1v.w};
#pragma unroll
    for (int ii = 0; ii < 4; ii++)
#pragma unroll
      for (int jj = 0; jj < 8; jj++) acc[ii][jj] = fmaf(av[ii], wv[jj], acc[ii][jj]);
  }
}

// ---------------------------------------------------------------------------
// conv3 stats pass: bn2+relu(Y2) -> conv3(64->128)+bias, accumulate stats3 only
// ---------------------------------------------------------------------------
__global__ __launch_bounds__(256) void conv3stats_kernel(const u16* __restrict__ Y2,
                                                         const float* __restrict__ w3,
                                                         const float* __restrict__ b3,
                                                         const float* __restrict__ g2,
                                                         const float* __restrict__ be2,
                                                         float* __restrict__ stats) {
  __shared__ __align__(16) float As[64 * 64];
  __shared__ __align__(16) float Ws[64 * 128];
  __shared__ float sS[64], sT[64];
  __shared__ float ssum[128], ssq[128];
  const int t = threadIdx.x, blk = blockIdx.x;
  const int pbase = blk * 64;
  if (t < 64) {
    float mean = stats[128 + t] * (1.0f / NT_F);
    float var = stats[192 + t] * (1.0f / NT_F) - mean * mean;
    float s = g2[t] * rsqrtf(var + EPSV);
    sS[t] = s;
    sT[t] = be2[t] - mean * s;
  }
  if (t < 128) { ssum[t] = 0.f; ssq[t] = 0.f; }
  stage_W(w3, Ws, 64, 128, t);
  __syncthreads();
  stage_A_bn(Y2, pbase, t, As, sS, sT);
  __syncthreads();
  const int i = t & 15, j = t >> 4, ob = j * 8;
  float acc[4][8];
#pragma unroll
  for (int a = 0; a < 4; a++)
#pragma unroll
    for (int c2 = 0; c2 < 8; c2++) acc[a][c2] = 0.f;
  conv3_compute(As, Ws, i, ob, acc);
#pragma unroll
  for (int jj = 0; jj < 8; jj++) {
    float bl = b3[ob + jj];
    float s = 0.f, q2 = 0.f;
#pragma unroll
    for (int ii = 0; ii < 4; ii++) {
      float v = acc[ii][jj] + bl;
      s += v;
      q2 += v * v;
    }
    atomicAdd(&ssum[ob + jj], s);
    atomicAdd(&ssq[ob + jj], q2);
  }
  __syncthreads();
  if (t < 128) atomicAdd(&stats[256 + t], ssum[t]);
  else atomicAdd(&stats[384 + (t - 128)], ssq[t - 128]);
}

// ---------------------------------------------------------------------------
// maxout: recompute conv3, apply bn3 (bias folded), max over k=32, relu, store
// out[b][o][s] (o-major) at d_out+49152
// ---------------------------------------------------------------------------
__global__ __launch_bounds__(256) void maxout_kernel(const u16* __restrict__ Y2,
                                                     const float* __restrict__ w3,
                                                     const float* __restrict__ b3,
                                                     const float* __restrict__ g2,
                                                     const float* __restrict__ be2,
                                                     const float* __restrict__ g3,
                                                     const float* __restrict__ be3,
                                                     const float* __restrict__ stats,
                                                     float* __restrict__ outf) {
  __shared__ __align__(16) float As[64 * 64];
  __shared__ __align__(16) float Ws[64 * 128];
  __shared__ float sS2[64], sT2[64], sS3[128], sT3[128];
  const int t = threadIdx.x, blk = blockIdx.x;
  const int pbase = blk * 64;
  if (t < 64) {
    float mean = stats[128 + t] * (1.0f / NT_F);
    float var = stats[192 + t] * (1.0f / NT_F) - mean * mean;
    float s = g2[t] * rsqrtf(var + EPSV);
    sS2[t] = s;
    sT2[t] = be2[t] - mean * s;
  }
  if (t < 128) {
    float mean = stats[256 + t] * (1.0f / NT_F);
    float var = stats[384 + t] * (1.0f / NT_F) - mean * mean;
    float s = g3[t] * rsqrtf(var + EPSV);
    sS3[t] = s;
    sT3[t] = be3[t] + (b3[t] - mean) * s;  // bias folded into shift
  }
  stage_W(w3, Ws, 64, 128, t);
  __syncthreads();
  stage_A_bn(Y2, pbase, t, As, sS2, sT2);
  __syncthreads();
  const int i = t & 15, j = t >> 4, ob = j * 8;
  float acc[4][8];
#pragma unroll
  for (int a = 0; a < 4; a++)
#pragma unroll
    for (int c2 = 0; c2 < 8; c2++) acc[a][c2] = 0.f;
  conv3_compute(As, Ws, i, ob, acc);
  float m[8];
#pragma unroll
  for (int jj = 0; jj < 8; jj++) {
    float sf = sS3[ob + jj], tf = sT3[ob + jj];
    float v0 = fmaf(acc[0][jj], sf, tf);
    float v1 = fmaf(acc[1][jj], sf, tf);
    float v2 = fmaf(acc[2][jj], sf, tf);
    float v3 = fmaf(acc[3][jj], sf, tf);
    m[jj] = fmaxf(fmaxf(v0, v1), fmaxf(v2, v3));
  }
#pragma unroll
  for (int off = 1; off < 8; off <<= 1)
#pragma unroll
    for (int jj = 0; jj < 8; jj++) m[jj] = fmaxf(m[jj], __shfl_xor(m[jj], off));
  if ((i & 7) == 0) {
    int gidx = blk * 2 + (i >> 3);
    int b = gidx >> 10, s2 = gidx & 1023;
#pragma unroll
    for (int jj = 0; jj < 8; jj++)
      outf[((size_t)b * 128 + ob + jj) * 1024 + s2] = fmaxf(m[jj], 0.f);
  }
}

// ---------------------------------------------------------------------------
// launch
// ---------------------------------------------------------------------------
extern "C" void kernel_launch(void* const* d_in, const int* in_sizes, int n_in,
                              void* d_out, int out_size, void* d_ws, size_t ws_size,
                              hipStream_t stream) {
  const float* xyz = (const float*)d_in[0];
  const float* pts = (const float*)d_in[1];
  const float* w1 = (const float*)d_in[2];
  const float* b1 = (const float*)d_in[3];
  const float* g1 = (const float*)d_in[4];
  const float* be1 = (const float*)d_in[5];
  const float* w2 = (const float*)d_in[6];
  const float* b2 = (const float*)d_in[7];
  const float* g2 = (const float*)d_in[8];
  const float* be2 = (const float*)d_in[9];
  const float* w3 = (const float*)d_in[10];
  const float* b3 = (const float*)d_in[11];
  const float* g3 = (const float*)d_in[12];
  const float* be3 = (const float*)d_in[13];

  float* out = (float*)d_out;
  float* newxyz = out;                 // 16*1024*3 = 49152 floats
  float* outfeat = out + 49152;        // 16*128*1024 floats

  char* ws = (char*)d_ws;
  int* ballidx = (int*)ws;                              // 2 MB
  float* stats = (float*)(ws + 2097152);                // 512 floats
  u16* Y1 = (u16*)(ws + 4194304);                       // 64 MiB (bf16)
  u16* Y2 = (u16*)(ws + 71303168);                      // 64 MiB (bf16)

  hipMemsetAsync(stats, 0, 512 * sizeof(float), stream);

  fps_kernel<<<16, 256, 0, stream>>>(xyz, newxyz);
  ballq_kernel<<<64, 256, 0, stream>>>(xyz, newxyz, ballidx);
  gemm1_kernel<<<8192, 256, 0, stream>>>(xyz, pts, w1, b1, newxyz, ballidx, Y1, stats);
  gemm2_kernel<<<8192, 256, 0, stream>>>(Y1, w2, b2, g1, be1, stats, Y2);
  conv3stats_kernel<<<8192, 256, 0, stream>>>(Y2, w3, b3, g2, be2, stats);
  maxout_kernel<<<8192, 256, 0, stream>>>(Y2, w3, b3, g2, be2, g3, be3, stats, outfeat);
}

// Round 2
// 1910.131 us; speedup vs baseline: 1.9397x; 1.9397x over previous
//
#include <hip/hip_runtime.h>
#include <hip/hip_bf16.h>

typedef unsigned short u16;
typedef unsigned long long u64;

#define NN 8192
#define SSAMP 1024
#define KK 32
#define NT_F 524288.0f
#define EPSV 1e-5f

__device__ __forceinline__ u64 umax64(u64 a, u64 b) { return a > b ? a : b; }

// ---------------------------------------------------------------------------
// FPS v2: one block/batch, 512 threads, 16 pts/thread in registers.
// u64 key = (float_bits(dist) << 32) | ~idx  -> max key == max dist, tie -> min idx.
// USE_LDS=1: coords cached in 96KB dynamic LDS (centroid fetch ~120cyc).
// Single barrier per iteration via double-buffered candidate slots.
// Distance arithmetic identical to reference: (dx*dx + dy*dy) + dz*dz, rn ops.
// ---------------------------------------------------------------------------
template <int USE_LDS>
__global__ __launch_bounds__(512, 1) void fps_kernel_t(const float* __restrict__ xyz,
                                                       float* __restrict__ newxyz) {
  extern __shared__ float cbuf[];  // [3*NN] when USE_LDS
  const int b = blockIdx.x, t = threadIdx.x;
  const float* base = xyz + (size_t)b * NN * 3;
  float* sx = cbuf;
  float* sy = cbuf + NN;
  float* sz = cbuf + 2 * NN;
  __shared__ u64 cand[2][8];
  float X[16], Y[16], Z[16], D[16];
#pragma unroll
  for (int j = 0; j < 16; j++) {
    int p = j * 512 + t;
    float x = base[p * 3 + 0], y = base[p * 3 + 1], z = base[p * 3 + 2];
    X[j] = x; Y[j] = y; Z[j] = z; D[j] = 1e10f;
    if (USE_LDS) { sx[p] = x; sy[p] = y; sz[p] = z; }
  }
  const unsigned lo0 = ~(unsigned)t;
  __syncthreads();
  int cur = 0;
  const int w = t >> 6;
  for (int it = 0; it < SSAMP; it++) {
    float cx, cy, cz;
    if (USE_LDS) { cx = sx[cur]; cy = sy[cur]; cz = sz[cur]; }
    else { cx = base[cur * 3 + 0]; cy = base[cur * 3 + 1]; cz = base[cur * 3 + 2]; }
    if (t == 0) {
      float* o = newxyz + ((size_t)b * SSAMP + it) * 3;
      o[0] = cx; o[1] = cy; o[2] = cz;
    }
    u64 k0 = 0, k1 = 0, k2 = 0, k3 = 0;
#pragma unroll
    for (int j = 0; j < 16; j++) {
      float dx = __fsub_rn(X[j], cx);
      float dy = __fsub_rn(Y[j], cy);
      float dz = __fsub_rn(Z[j], cz);
      float d = __fadd_rn(__fadd_rn(__fmul_rn(dx, dx), __fmul_rn(dy, dy)), __fmul_rn(dz, dz));
      float dm = fminf(D[j], d);
      D[j] = dm;
      u64 key = ((u64)__float_as_uint(dm) << 32) | (u64)(unsigned)(lo0 - (unsigned)(j << 9));
      if ((j & 3) == 0) k0 = umax64(k0, key);
      else if ((j & 3) == 1) k1 = umax64(k1, key);
      else if ((j & 3) == 2) k2 = umax64(k2, key);
      else k3 = umax64(k3, key);
    }
    u64 best = umax64(umax64(k0, k1), umax64(k2, k3));
#pragma unroll
    for (int off = 1; off < 64; off <<= 1) {
      u64 o = __shfl_xor(best, off);
      best = umax64(best, o);
    }
    const int s = it & 1;
    if ((t & 63) == 0) cand[s][w] = best;
    __syncthreads();
    u64 c0 = cand[s][0], c1 = cand[s][1], c2 = cand[s][2], c3 = cand[s][3];
    u64 c4 = cand[s][4], c5 = cand[s][5], c6 = cand[s][6], c7 = cand[s][7];
    u64 a0 = umax64(c0, c1), a1 = umax64(c2, c3), a2 = umax64(c4, c5), a3 = umax64(c6, c7);
    best = umax64(umax64(a0, a1), umax64(a2, a3));
    cur = (int)(~(unsigned)(best & 0xFFFFFFFFull));
  }
}

// ---------------------------------------------------------------------------
// Ball query v2: one WAVE per centroid, 64-pt chunks, ballot + rank compaction.
// Exact semantics: first 32 indices (ascending) with d <= r^2, pad with first.
// ---------------------------------------------------------------------------
__global__ __launch_bounds__(256) void ballq_kernel(const float* __restrict__ xyz,
                                                    const float* __restrict__ newxyz,
                                                    int* __restrict__ ballidx) {
  const int wid = blockIdx.x * 4 + (threadIdx.x >> 6);  // 0..16383
  const int lane = threadIdx.x & 63;
  const int b = wid >> 10;
  const float* base = xyz + (size_t)b * NN * 3;
  const float cx = newxyz[wid * 3 + 0];
  const float cy = newxyz[wid * 3 + 1];
  const float cz = newxyz[wid * 3 + 2];
  int* op = ballidx + (size_t)wid * KK;
  int cnt = 0, first = -1;
  for (int p0 = 0; p0 < NN; p0 += 64) {
    const int p = p0 + lane;
    float dx = __fsub_rn(cx, base[p * 3 + 0]);
    float dy = __fsub_rn(cy, base[p * 3 + 1]);
    float dz = __fsub_rn(cz, base[p * 3 + 2]);
    float d = __fadd_rn(__fadd_rn(__fmul_rn(dx, dx), __fmul_rn(dy, dy)), __fmul_rn(dz, dz));
    bool hit = d <= 0.04f;
    u64 m = __ballot(hit);
    if (m) {
      if (first < 0) first = p0 + __ffsll((long long)m) - 1;
      int rank = __popcll(m & ((1ull << lane) - 1ull));
      int slot = cnt + rank;
      if (hit && slot < KK) op[slot] = p;
      cnt += __popcll(m);
      if (cnt >= KK) break;
    }
  }
  if (cnt < KK && lane >= cnt && lane < KK) op[lane] = first;
}

// ---------------------------------------------------------------------------
// Shared helpers for the conv/BN pipeline
// ---------------------------------------------------------------------------
__device__ __forceinline__ void stage_W(const float* __restrict__ w, float* Ws, int K, int O, int t) {
  for (int i2 = t; i2 < K * O; i2 += 256) {
    int c = i2 / O, o = i2 % O;
    Ws[i2] = w[o * K + c];  // Ws[c*O + o] = w[o][c]
  }
}

__device__ __forceinline__ void stage_A_bn(const u16* __restrict__ Yin, int pbase, int t,
                                           float* As, const float* sS, const float* sT) {
  int r = t >> 2, q = t & 3;
  const ushort4* yr = (const ushort4*)(Yin + ((size_t)(pbase + r)) * 64);
#pragma unroll
  for (int l = 0; l < 4; l++) {
    ushort4 u = yr[q * 4 + l];
    int c = q * 16 + l * 4;
    union { ushort4 u4; __hip_bfloat16 h[4]; } pk;
    pk.u4 = u;
#pragma unroll
    for (int m2 = 0; m2 < 4; m2++) {
      float f = __bfloat162float(pk.h[m2]);
      f = fmaf(f, sS[c + m2], sT[c + m2]);
      As[(c + m2) * 64 + r] = fmaxf(f, 0.f);
    }
  }
}

// ---------------------------------------------------------------------------
// GEMM1: gather(points, xyz_norm) -> conv1(67->64)+bias, Y bf16, stats1 buckets
// ---------------------------------------------------------------------------
__global__ __launch_bounds__(256) void gemm1_kernel(const float* __restrict__ xyz,
                                                    const float* __restrict__ pts,
                                                    const float* __restrict__ w1,
                                                    const float* __restrict__ b1,
                                                    const float* __restrict__ newxyz,
                                                    const int* __restrict__ ballidx,
                                                    u16* __restrict__ Y1,
                                                    float* __restrict__ bkt) {
  __shared__ __align__(16) float As[67 * 64];
  __shared__ __align__(16) float Ws[67 * 64];
  __shared__ int sidx[64];
  __shared__ float snx[6];
  __shared__ float ssum[64], ssq[64];
  const int t = threadIdx.x, blk = blockIdx.x;
  const int pbase = blk * 64;
  const int g0 = pbase >> 5;
  const int b = g0 >> 10;
  if (t < 64) { sidx[t] = ballidx[pbase + t]; ssum[t] = 0.f; ssq[t] = 0.f; }
  if (t < 6) snx[t] = newxyz[(size_t)g0 * 3 + t];
  stage_W(w1, Ws, 67, 64, t);
  __syncthreads();
  {
    int r = t >> 2, q = t & 3;
    const float4* prow = (const float4*)(pts + ((size_t)b * NN + sidx[r]) * 64);
#pragma unroll
    for (int l = 0; l < 4; l++) {
      float4 v = prow[q * 4 + l];
      int c = 3 + q * 16 + l * 4;
      As[(c + 0) * 64 + r] = v.x;
      As[(c + 1) * 64 + r] = v.y;
      As[(c + 2) * 64 + r] = v.z;
      As[(c + 3) * 64 + r] = v.w;
    }
  }
  if (t < 64) {
    const float* xp = xyz + ((size_t)b * NN + sidx[t]) * 3;
    int g = t >> 5;
    As[0 * 64 + t] = xp[0] - snx[g * 3 + 0];
    As[1 * 64 + t] = xp[1] - snx[g * 3 + 1];
    As[2 * 64 + t] = xp[2] - snx[g * 3 + 2];
  }
  __syncthreads();
  const int i = t & 15, j = t >> 4;
  float acc[4][4];
#pragma unroll
  for (int a = 0; a < 4; a++)
#pragma unroll
    for (int c2 = 0; c2 < 4; c2++) acc[a][c2] = 0.f;
#pragma unroll 4
  for (int c = 0; c < 67; c++) {
    float4 a4 = *(const float4*)&As[c * 64 + i * 4];
    float4 w4 = *(const float4*)&Ws[c * 64 + j * 4];
    float av[4] = {a4.x, a4.y, a4.z, a4.w};
    float wv[4] = {w4.x, w4.y, w4.z, w4.w};
#pragma unroll
    for (int ii = 0; ii < 4; ii++)
#pragma unroll
      for (int jj = 0; jj < 4; jj++) acc[ii][jj] = fmaf(av[ii], wv[jj], acc[ii][jj]);
  }
  float bl[4];
#pragma unroll
  for (int jj = 0; jj < 4; jj++) bl[jj] = b1[j * 4 + jj];
#pragma unroll
  for (int ii = 0; ii < 4; ii++) {
    union { ushort4 u4; __hip_bfloat16 h[4]; } pk;
#pragma unroll
    for (int jj = 0; jj < 4; jj++) {
      float y = acc[ii][jj] + bl[jj];
      acc[ii][jj] = y;
      pk.h[jj] = __float2bfloat16(y);
    }
    *(ushort4*)&Y1[((size_t)(pbase + i * 4 + ii)) * 64 + j * 4] = pk.u4;
  }
#pragma unroll
  for (int jj = 0; jj < 4; jj++) {
    float s = 0.f, q2 = 0.f;
#pragma unroll
    for (int ii = 0; ii < 4; ii++) { float v = acc[ii][jj]; s += v; q2 += v * v; }
    atomicAdd(&ssum[j * 4 + jj], s);
    atomicAdd(&ssq[j * 4 + jj], q2);
  }
  __syncthreads();
  float* bb = bkt + (size_t)(blk & 63) * 512;
  if (t < 64) atomicAdd(&bb[t], ssum[t]);
  else if (t < 128) atomicAdd(&bb[64 + (t - 64)], ssq[t - 64]);
}

// ---------------------------------------------------------------------------
// collapse: dst[e] = sum over 64 buckets of bkt[u][e], e in [0,512)
// ---------------------------------------------------------------------------
__global__ __launch_bounds__(256) void collapse_kernel(const float* __restrict__ bkt,
                                                       float* __restrict__ dst) {
  int e = blockIdx.x * 256 + threadIdx.x;
  float s = 0.f;
#pragma unroll 8
  for (int u = 0; u < 64; u++) s += bkt[u * 512 + e];
  dst[e] = s;
}

// ---------------------------------------------------------------------------
// GEMM2: bn1+relu(Y) -> conv2(64->64)+bias, Y bf16 IN-PLACE, stats2 buckets
// ---------------------------------------------------------------------------
__global__ __launch_bounds__(256) void gemm2_kernel(u16* __restrict__ Y,
                                                    const float* __restrict__ w2,
                                                    const float* __restrict__ b2,
                                                    const float* __restrict__ g1,
                                                    const float* __restrict__ be1,
                                                    const float* __restrict__ statsC,
                                                    float* __restrict__ bkt) {
  __shared__ __align__(16) float As[64 * 64];
  __shared__ __align__(16) float Ws[64 * 64];
  __shared__ float sS[64], sT[64];
  __shared__ float ssum[64], ssq[64];
  const int t = threadIdx.x, blk = blockIdx.x;
  const int pbase = blk * 64;
  if (t < 64) {
    float mean = statsC[t] * (1.0f / NT_F);
    float var = statsC[64 + t] * (1.0f / NT_F) - mean * mean;
    float s = g1[t] * rsqrtf(var + EPSV);
    sS[t] = s;
    sT[t] = be1[t] - mean * s;
    ssum[t] = 0.f; ssq[t] = 0.f;
  }
  stage_W(w2, Ws, 64, 64, t);
  __syncthreads();
  stage_A_bn(Y, pbase, t, As, sS, sT);
  __syncthreads();
  const int i = t & 15, j = t >> 4;
  float acc[4][4];
#pragma unroll
  for (int a = 0; a < 4; a++)
#pragma unroll
    for (int c2 = 0; c2 < 4; c2++) acc[a][c2] = 0.f;
#pragma unroll 4
  for (int c = 0; c < 64; c++) {
    float4 a4 = *(const float4*)&As[c * 64 + i * 4];
    float4 w4 = *(const float4*)&Ws[c * 64 + j * 4];
    float av[4] = {a4.x, a4.y, a4.z, a4.w};
    float wv[4] = {w4.x, w4.y, w4.z, w4.w};
#pragma unroll
    for (int ii = 0; ii < 4; ii++)
#pragma unroll
      for (int jj = 0; jj < 4; jj++) acc[ii][jj] = fmaf(av[ii], wv[jj], acc[ii][jj]);
  }
  float bl[4];
#pragma unroll
  for (int jj = 0; jj < 4; jj++) bl[jj] = b2[j * 4 + jj];
#pragma unroll
  for (int ii = 0; ii < 4; ii++) {
    union { ushort4 u4; __hip_bfloat16 h[4]; } pk;
#pragma unroll
    for (int jj = 0; jj < 4; jj++) {
      float y = acc[ii][jj] + bl[jj];
      acc[ii][jj] = y;
      pk.h[jj] = __float2bfloat16(y);
    }
    *(ushort4*)&Y[((size_t)(pbase + i * 4 + ii)) * 64 + j * 4] = pk.u4;
  }
#pragma unroll
  for (int jj = 0; jj < 4; jj++) {
    float s = 0.f, q2 = 0.f;
#pragma unroll
    for (int ii = 0; ii < 4; ii++) { float v = acc[ii][jj]; s += v; q2 += v * v; }
    atomicAdd(&ssum[j * 4 + jj], s);
    atomicAdd(&ssq[j * 4 + jj], q2);
  }
  __syncthreads();
  float* bb = bkt + (size_t)(blk & 63) * 512;
  if (t < 64) atomicAdd(&bb[128 + t], ssum[t]);
  else if (t < 128) atomicAdd(&bb[192 + (t - 64)], ssq[t - 64]);
}

// ---------------------------------------------------------------------------
// conv3max: bn2+relu(Y) -> conv3(64->128)+bias = y3; accumulate stats3 buckets
// AND per-(group,ch) max/min of y3 (BN3 affine is monotone; finalize picks).
// ---------------------------------------------------------------------------
__global__ __launch_bounds__(256) void conv3max_kernel(const u16* __restrict__ Y,
                                                       const float* __restrict__ w3,
                                                       const float* __restrict__ b3,
                                                       const float* __restrict__ g2,
                                                       const float* __restrict__ be2,
                                                       const float* __restrict__ statsC,
                                                       float* __restrict__ bkt,
                                                       float* __restrict__ gmax,
                                                       float* __restrict__ gmin) {
  __shared__ __align__(16) float As[64 * 64];
  __shared__ __align__(16) float Ws[64 * 128];
  __shared__ float sS[64], sT[64];
  __shared__ float ssum[128], ssq[128];
  const int t = threadIdx.x, blk = blockIdx.x;
  const int pbase = blk * 64;
  if (t < 64) {
    float mean = statsC[128 + t] * (1.0f / NT_F);
    float var = statsC[192 + t] * (1.0f / NT_F) - mean * mean;
    float s = g2[t] * rsqrtf(var + EPSV);
    sS[t] = s;
    sT[t] = be2[t] - mean * s;
  }
  if (t < 128) { ssum[t] = 0.f; ssq[t] = 0.f; }
  stage_W(w3, Ws, 64, 128, t);
  __syncthreads();
  stage_A_bn(Y, pbase, t, As, sS, sT);
  __syncthreads();
  const int i = t & 15, j = t >> 4, ob = j * 8;
  float acc[4][8];
#pragma unroll
  for (int a = 0; a < 4; a++)
#pragma unroll
    for (int c2 = 0; c2 < 8; c2++) acc[a][c2] = 0.f;
#pragma unroll 4
  for (int c = 0; c < 64; c++) {
    float4 a4 = *(const float4*)&As[c * 64 + i * 4];
    float4 w0 = *(const float4*)&Ws[c * 128 + ob];
    float4 w1v = *(const float4*)&Ws[c * 128 + ob + 4];
    float av[4] = {a4.x, a4.y, a4.z, a4.w};
    float wv[8] = {w0.x, w0.y, w0.z, w0.w, w1v.x, w1v.y, w1v.z, w1v.w};
#pragma unroll
    for (int ii = 0; ii < 4; ii++)
#pragma unroll
      for (int jj = 0; jj < 8; jj++) acc[ii][jj] = fmaf(av[ii], wv[jj], acc[ii][jj]);
  }
  float m[8], mn[8];
#pragma unroll
  for (int jj = 0; jj < 8; jj++) {
    float bl = b3[ob + jj];
    float v0 = acc[0][jj] + bl, v1 = acc[1][jj] + bl;
    float v2 = acc[2][jj] + bl, v3 = acc[3][jj] + bl;
    atomicAdd(&ssum[ob + jj], (v0 + v1) + (v2 + v3));
    atomicAdd(&ssq[ob + jj], (v0 * v0 + v1 * v1) + (v2 * v2 + v3 * v3));
    m[jj] = fmaxf(fmaxf(v0, v1), fmaxf(v2, v3));
    mn[jj] = fminf(fminf(v0, v1), fminf(v2, v3));
  }
#pragma unroll
  for (int off = 1; off < 8; off <<= 1)
#pragma unroll
    for (int jj = 0; jj < 8; jj++) {
      m[jj] = fmaxf(m[jj], __shfl_xor(m[jj], off));
      mn[jj] = fminf(mn[jj], __shfl_xor(mn[jj], off));
    }
  if ((i & 7) == 0) {
    int gidx = blk * 2 + (i >> 3);
#pragma unroll
    for (int jj = 0; jj < 8; jj++) {
      gmax[(size_t)gidx * 128 + ob + jj] = m[jj];
      gmin[(size_t)gidx * 128 + ob + jj] = mn[jj];
    }
  }
  __syncthreads();
  float* bb = bkt + (size_t)(blk & 63) * 512;
  if (t < 128) atomicAdd(&bb[256 + t], ssum[t]);
  else atomicAdd(&bb[384 + (t - 128)], ssq[t - 128]);
}

// ---------------------------------------------------------------------------
// finalize: out[b][o][s] = relu( sel * s3 + t3 ), sel = (s3>0 ? gmax : gmin)
// ---------------------------------------------------------------------------
__global__ __launch_bounds__(256) void finalize_kernel(const float* __restrict__ gmax,
                                                       const float* __restrict__ gmin,
                                                       const float* __restrict__ statsC,
                                                       const float* __restrict__ g3,
                                                       const float* __restrict__ be3,
                                                       float* __restrict__ outf) {
  int gi = blockIdx.x * 256 + threadIdx.x;  // 16*128*1024
  int s = gi & 1023;
  int o = (gi >> 10) & 127;
  int b = gi >> 17;
  float mean = statsC[256 + o] * (1.0f / NT_F);
  float var = statsC[384 + o] * (1.0f / NT_F) - mean * mean;
  float sc = g3[o] * rsqrtf(var + EPSV);
  float sh = be3[o] - mean * sc;
  size_t gidx = (size_t)(b * 1024 + s) * 128 + o;
  float v = sc > 0.f ? gmax[gidx] : gmin[gidx];
  outf[gi] = fmaxf(fmaf(v, sc, sh), 0.f);
}

// ---------------------------------------------------------------------------
// launch
// ---------------------------------------------------------------------------
extern "C" void kernel_launch(void* const* d_in, const int* in_sizes, int n_in,
                              void* d_out, int out_size, void* d_ws, size_t ws_size,
                              hipStream_t stream) {
  const float* xyz = (const float*)d_in[0];
  const float* pts = (const float*)d_in[1];
  const float* w1 = (const float*)d_in[2];
  const float* b1 = (const float*)d_in[3];
  const float* g1 = (const float*)d_in[4];
  const float* be1 = (const float*)d_in[5];
  const float* w2 = (const float*)d_in[6];
  const float* b2 = (const float*)d_in[7];
  const float* g2 = (const float*)d_in[8];
  const float* be2 = (const float*)d_in[9];
  const float* w3 = (const float*)d_in[10];
  const float* b3 = (const float*)d_in[11];
  const float* g3 = (const float*)d_in[12];
  const float* be3 = (const float*)d_in[13];

  float* out = (float*)d_out;
  float* newxyz = out;            // 16*1024*3
  float* outfeat = out + 49152;   // 16*128*1024

  char* ws = (char*)d_ws;
  int* ballidx = (int*)ws;                          // 2 MB
  float* bkt = (float*)(ws + (2 << 20));            // 64*512*4 = 128 KB
  float* statsC = (float*)(ws + (2 << 20) + 131072);// 2 KB
  float* gmax = (float*)(ws + (4 << 20));           // 8 MB
  float* gmin = (float*)(ws + (12 << 20));          // 8 MB
  u16* Y = (u16*)(ws + (20 << 20));                 // 64 MiB (in-place Y1->Y2)

  hipMemsetAsync(bkt, 0, 64 * 512 * sizeof(float), stream);

  // FPS: prefer 96KB-LDS coord-cache variant; fall back to global-fetch.
  bool use_lds = false;
  {
    hipError_t e = hipFuncSetAttribute((const void*)fps_kernel_t<1>,
                                       hipFuncAttributeMaxDynamicSharedMemorySize, 98304);
    if (e == hipSuccess) {
      int nb = 0;
      hipError_t e2 = hipOccupancyMaxActiveBlocksPerMultiprocessor(
          &nb, (const void*)fps_kernel_t<1>, 512, 98304);
      use_lds = (e2 == hipSuccess && nb >= 1);
    }
  }
  if (use_lds)
    fps_kernel_t<1><<<16, 512, 98304, stream>>>(xyz, newxyz);
  else
    fps_kernel_t<0><<<16, 512, 0, stream>>>(xyz, newxyz);

  ballq_kernel<<<4096, 256, 0, stream>>>(xyz, newxyz, ballidx);
  gemm1_kernel<<<8192, 256, 0, stream>>>(xyz, pts, w1, b1, newxyz, ballidx, Y, bkt);
  collapse_kernel<<<2, 256, 0, stream>>>(bkt, statsC);
  gemm2_kernel<<<8192, 256, 0, stream>>>(Y, w2, b2, g1, be1, statsC, bkt);
  collapse_kernel<<<2, 256, 0, stream>>>(bkt, statsC);
  conv3max_kernel<<<8192, 256, 0, stream>>>(Y, w3, b3, g2, be2, statsC, bkt, gmax, gmin);
  collapse_kernel<<<2, 256, 0, stream>>>(bkt, statsC);
  finalize_kernel<<<8192, 256, 0, stream>>>(gmax, gmin, statsC, g3, be3, outfeat);
}

// Round 3
// 1771.243 us; speedup vs baseline: 2.0918x; 1.0784x over previous
//
#include <hip/hip_runtime.h>
#include <hip/hip_bf16.h>

typedef unsigned short u16;
typedef unsigned long long u64;

#define NN 8192
#define SSAMP 1024
#define KK 32
#define NT_F 524288.0f
#define EPSV 1e-5f

__device__ __forceinline__ u64 umax64(u64 a, u64 b) { return a > b ? a : b; }

// One DPP reduction step on a u64 (hi,lo) max-key. Identity 0 can't win
// (dist>=0 packed in hi; lo=~idx != 0), so bound_ctrl-0 fill is safe.
template <int C>
__device__ __forceinline__ void dppstep(unsigned& hi, unsigned& lo) {
  unsigned h2 = (unsigned)__builtin_amdgcn_update_dpp(0, (int)hi, C, 0xF, 0xF, true);
  unsigned l2 = (unsigned)__builtin_amdgcn_update_dpp(0, (int)lo, C, 0xF, 0xF, true);
  u64 a = ((u64)hi << 32) | lo;
  u64 b = ((u64)h2 << 32) | l2;
  bool g = b > a;
  hi = g ? h2 : hi;
  lo = g ? l2 : lo;
}

// Full wave64 max-reduce; valid result in lane 63.
__device__ __forceinline__ u64 wave_max_key(u64 key) {
  unsigned hi = (unsigned)(key >> 32), lo = (unsigned)key;
  dppstep<0x111>(hi, lo);  // row_shr:1
  dppstep<0x112>(hi, lo);  // row_shr:2
  dppstep<0x114>(hi, lo);  // row_shr:4
  dppstep<0x118>(hi, lo);  // row_shr:8
  dppstep<0x142>(hi, lo);  // row_bcast:15
  dppstep<0x143>(hi, lo);  // row_bcast:31
  return ((u64)hi << 32) | lo;
}

// ---------------------------------------------------------------------------
// FPS v3: one block/batch, 512 threads, 16 pts/thread in registers.
// Per-thread argmax via fmax+cndmask; wave reduce via DPP (VALU-only);
// cross-wave via double-buffered LDS slots, single barrier per iteration.
// Distance arithmetic identical to reference: (dx*dx + dy*dy) + dz*dz, rn ops.
// ---------------------------------------------------------------------------
template <int USE_LDS>
__global__ __launch_bounds__(512, 1) void fps_kernel_t(const float* __restrict__ xyz,
                                                       float* __restrict__ newxyz) {
  extern __shared__ float cbuf[];  // [3*NN] when USE_LDS
  const int b = blockIdx.x, t = threadIdx.x;
  const float* base = xyz + (size_t)b * NN * 3;
  float* sx = cbuf;
  float* sy = cbuf + NN;
  float* sz = cbuf + 2 * NN;
  __shared__ u64 cand[2][8];
  float X[16], Y[16], Z[16], D[16];
#pragma unroll
  for (int j = 0; j < 16; j++) {
    int p = j * 512 + t;
    float x = base[p * 3 + 0], y = base[p * 3 + 1], z = base[p * 3 + 2];
    X[j] = x; Y[j] = y; Z[j] = z; D[j] = 1e10f;
    if (USE_LDS) { sx[p] = x; sy[p] = y; sz[p] = z; }
  }
  __syncthreads();
  int cur = 0;
  const int w = t >> 6;
  for (int it = 0; it < SSAMP; it++) {
    float cx, cy, cz;
    if (USE_LDS) { cx = sx[cur]; cy = sy[cur]; cz = sz[cur]; }
    else { cx = base[cur * 3 + 0]; cy = base[cur * 3 + 1]; cz = base[cur * 3 + 2]; }
    if (t == 0) {
      float* o = newxyz + ((size_t)b * SSAMP + it) * 3;
      o[0] = cx; o[1] = cy; o[2] = cz;
    }
    float bestd = -1.0f;
    int bj = 0;
#pragma unroll
    for (int j = 0; j < 16; j++) {
      float dx = __fsub_rn(X[j], cx);
      float dy = __fsub_rn(Y[j], cy);
      float dz = __fsub_rn(Z[j], cz);
      float d = __fadd_rn(__fadd_rn(__fmul_rn(dx, dx), __fmul_rn(dy, dy)), __fmul_rn(dz, dz));
      float dm = fminf(D[j], d);
      D[j] = dm;
      bool g = dm > bestd;   // strict >: first occurrence (min j) kept on ties
      bestd = g ? dm : bestd;
      bj = g ? j : bj;
    }
    u64 key = ((u64)__float_as_uint(bestd) << 32) |
              (u64)(unsigned)~(unsigned)(bj * 512 + t);
    key = wave_max_key(key);  // lane 63 valid
    const int s = it & 1;
    if ((t & 63) == 63) cand[s][w] = key;
    __syncthreads();
    u64 c0 = cand[s][0], c1 = cand[s][1], c2 = cand[s][2], c3 = cand[s][3];
    u64 c4 = cand[s][4], c5 = cand[s][5], c6 = cand[s][6], c7 = cand[s][7];
    u64 a0 = umax64(c0, c1), a1 = umax64(c2, c3), a2 = umax64(c4, c5), a3 = umax64(c6, c7);
    u64 best = umax64(umax64(a0, a1), umax64(a2, a3));
    cur = (int)(~(unsigned)(best & 0xFFFFFFFFull));
  }
}

// ---------------------------------------------------------------------------
// Ball query: one WAVE per centroid, 64-pt chunks, ballot + rank compaction.
// Exact semantics: first 32 indices (ascending) with d <= r^2, pad with first.
// ---------------------------------------------------------------------------
__global__ __launch_bounds__(256) void ballq_kernel(const float* __restrict__ xyz,
                                                    const float* __restrict__ newxyz,
                                                    int* __restrict__ ballidx) {
  const int wid = blockIdx.x * 4 + (threadIdx.x >> 6);  // 0..16383
  const int lane = threadIdx.x & 63;
  const int b = wid >> 10;
  const float* base = xyz + (size_t)b * NN * 3;
  const float cx = newxyz[wid * 3 + 0];
  const float cy = newxyz[wid * 3 + 1];
  const float cz = newxyz[wid * 3 + 2];
  int* op = ballidx + (size_t)wid * KK;
  int cnt = 0, first = -1;
  for (int p0 = 0; p0 < NN; p0 += 64) {
    const int p = p0 + lane;
    float dx = __fsub_rn(cx, base[p * 3 + 0]);
    float dy = __fsub_rn(cy, base[p * 3 + 1]);
    float dz = __fsub_rn(cz, base[p * 3 + 2]);
    float d = __fadd_rn(__fadd_rn(__fmul_rn(dx, dx), __fmul_rn(dy, dy)), __fmul_rn(dz, dz));
    bool hit = d <= 0.04f;
    u64 m = __ballot(hit);
    if (m) {
      if (first < 0) first = p0 + __ffsll((long long)m) - 1;
      int rank = __popcll(m & ((1ull << lane) - 1ull));
      int slot = cnt + rank;
      if (hit && slot < KK) op[slot] = p;
      cnt += __popcll(m);
      if (cnt >= KK) break;
    }
  }
  if (cnt < KK && lane >= cnt && lane < KK) op[lane] = first;
}

// ---------------------------------------------------------------------------
// Shared helpers for the conv/BN pipeline
// ---------------------------------------------------------------------------
__device__ __forceinline__ void stage_W(const float* __restrict__ w, float* Ws, int K, int O, int t) {
  for (int i2 = t; i2 < K * O; i2 += 256) {
    int c = i2 / O, o = i2 % O;
    Ws[i2] = w[o * K + c];  // Ws[c*O + o] = w[o][c]
  }
}

__device__ __forceinline__ void stage_A_bn(const u16* __restrict__ Yin, int pbase, int t,
                                           float* As, const float* sS, const float* sT) {
  int r = t >> 2, q = t & 3;
  const ushort4* yr = (const ushort4*)(Yin + ((size_t)(pbase + r)) * 64);
#pragma unroll
  for (int l = 0; l < 4; l++) {
    ushort4 u = yr[q * 4 + l];
    int c = q * 16 + l * 4;
    union { ushort4 u4; __hip_bfloat16 h[4]; } pk;
    pk.u4 = u;
#pragma unroll
    for (int m2 = 0; m2 < 4; m2++) {
      float f = __bfloat162float(pk.h[m2]);
      f = fmaf(f, sS[c + m2], sT[c + m2]);
      As[(c + m2) * 64 + r] = fmaxf(f, 0.f);
    }
  }
}

// ---------------------------------------------------------------------------
// GEMM1: gather(points, xyz_norm) -> conv1(67->64)+bias, Y bf16, stats1 buckets
// ---------------------------------------------------------------------------
__global__ __launch_bounds__(256) void gemm1_kernel(const float* __restrict__ xyz,
                                                    const float* __restrict__ pts,
                                                    const float* __restrict__ w1,
                                                    const float* __restrict__ b1,
                                                    const float* __restrict__ newxyz,
                                                    const int* __restrict__ ballidx,
                                                    u16* __restrict__ Y1,
                                                    float* __restrict__ bkt) {
  __shared__ __align__(16) float As[67 * 64];
  __shared__ __align__(16) float Ws[67 * 64];
  __shared__ int sidx[64];
  __shared__ float snx[6];
  __shared__ float ssum[64], ssq[64];
  const int t = threadIdx.x, blk = blockIdx.x;
  const int pbase = blk * 64;
  const int g0 = pbase >> 5;
  const int b = g0 >> 10;
  if (t < 64) { sidx[t] = ballidx[pbase + t]; ssum[t] = 0.f; ssq[t] = 0.f; }
  if (t < 6) snx[t] = newxyz[(size_t)g0 * 3 + t];
  stage_W(w1, Ws, 67, 64, t);
  __syncthreads();
  {
    int r = t >> 2, q = t & 3;
    const float4* prow = (const float4*)(pts + ((size_t)b * NN + sidx[r]) * 64);
#pragma unroll
    for (int l = 0; l < 4; l++) {
      float4 v = prow[q * 4 + l];
      int c = 3 + q * 16 + l * 4;
      As[(c + 0) * 64 + r] = v.x;
      As[(c + 1) * 64 + r] = v.y;
      As[(c + 2) * 64 + r] = v.z;
      As[(c + 3) * 64 + r] = v.w;
    }
  }
  if (t < 64) {
    const float* xp = xyz + ((size_t)b * NN + sidx[t]) * 3;
    int g = t >> 5;
    As[0 * 64 + t] = xp[0] - snx[g * 3 + 0];
    As[1 * 64 + t] = xp[1] - snx[g * 3 + 1];
    As[2 * 64 + t] = xp[2] - snx[g * 3 + 2];
  }
  __syncthreads();
  const int i = t & 15, j = t >> 4;
  float acc[4][4];
#pragma unroll
  for (int a = 0; a < 4; a++)
#pragma unroll
    for (int c2 = 0; c2 < 4; c2++) acc[a][c2] = 0.f;
#pragma unroll 4
  for (int c = 0; c < 67; c++) {
    float4 a4 = *(const float4*)&As[c * 64 + i * 4];
    float4 w4 = *(const float4*)&Ws[c * 64 + j * 4];
    float av[4] = {a4.x, a4.y, a4.z, a4.w};
    float wv[4] = {w4.x, w4.y, w4.z, w4.w};
#pragma unroll
    for (int ii = 0; ii < 4; ii++)
#pragma unroll
      for (int jj = 0; jj < 4; jj++) acc[ii][jj] = fmaf(av[ii], wv[jj], acc[ii][jj]);
  }
  float bl[4];
#pragma unroll
  for (int jj = 0; jj < 4; jj++) bl[jj] = b1[j * 4 + jj];
#pragma unroll
  for (int ii = 0; ii < 4; ii++) {
    union { ushort4 u4; __hip_bfloat16 h[4]; } pk;
#pragma unroll
    for (int jj = 0; jj < 4; jj++) {
      float y = acc[ii][jj] + bl[jj];
      acc[ii][jj] = y;
      pk.h[jj] = __float2bfloat16(y);
    }
    *(ushort4*)&Y1[((size_t)(pbase + i * 4 + ii)) * 64 + j * 4] = pk.u4;
  }
#pragma unroll
  for (int jj = 0; jj < 4; jj++) {
    float s = 0.f, q2 = 0.f;
#pragma unroll
    for (int ii = 0; ii < 4; ii++) { float v = acc[ii][jj]; s += v; q2 += v * v; }
    atomicAdd(&ssum[j * 4 + jj], s);
    atomicAdd(&ssq[j * 4 + jj], q2);
  }
  __syncthreads();
  float* bb = bkt + (size_t)(blk & 63) * 512;
  if (t < 64) atomicAdd(&bb[t], ssum[t]);
  else if (t < 128) atomicAdd(&bb[64 + (t - 64)], ssq[t - 64]);
}

// ---------------------------------------------------------------------------
// collapse: dst[e] = sum over 64 buckets of bkt[u][e], e in [0,512)
// ---------------------------------------------------------------------------
__global__ __launch_bounds__(256) void collapse_kernel(const float* __restrict__ bkt,
                                                       float* __restrict__ dst) {
  int e = blockIdx.x * 256 + threadIdx.x;
  float s = 0.f;
#pragma unroll 8
  for (int u = 0; u < 64; u++) s += bkt[u * 512 + e];
  dst[e] = s;
}

// ---------------------------------------------------------------------------
// GEMM2: bn1+relu(Y) -> conv2(64->64)+bias, Y bf16 IN-PLACE, stats2 buckets
// ---------------------------------------------------------------------------
__global__ __launch_bounds__(256) void gemm2_kernel(u16* __restrict__ Y,
                                                    const float* __restrict__ w2,
                                                    const float* __restrict__ b2,
                                                    const float* __restrict__ g1,
                                                    const float* __restrict__ be1,
                                                    const float* __restrict__ statsC,
                                                    float* __restrict__ bkt) {
  __shared__ __align__(16) float As[64 * 64];
  __shared__ __align__(16) float Ws[64 * 64];
  __shared__ float sS[64], sT[64];
  __shared__ float ssum[64], ssq[64];
  const int t = threadIdx.x, blk = blockIdx.x;
  const int pbase = blk * 64;
  if (t < 64) {
    float mean = statsC[t] * (1.0f / NT_F);
    float var = statsC[64 + t] * (1.0f / NT_F) - mean * mean;
    float s = g1[t] * rsqrtf(var + EPSV);
    sS[t] = s;
    sT[t] = be1[t] - mean * s;
    ssum[t] = 0.f; ssq[t] = 0.f;
  }
  stage_W(w2, Ws, 64, 64, t);
  __syncthreads();
  stage_A_bn(Y, pbase, t, As, sS, sT);
  __syncthreads();
  const int i = t & 15, j = t >> 4;
  float acc[4][4];
#pragma unroll
  for (int a = 0; a < 4; a++)
#pragma unroll
    for (int c2 = 0; c2 < 4; c2++) acc[a][c2] = 0.f;
#pragma unroll 4
  for (int c = 0; c < 64; c++) {
    float4 a4 = *(const float4*)&As[c * 64 + i * 4];
    float4 w4 = *(const float4*)&Ws[c * 64 + j * 4];
    float av[4] = {a4.x, a4.y, a4.z, a4.w};
    float wv[4] = {w4.x, w4.y, w4.z, w4.w};
#pragma unroll
    for (int ii = 0; ii < 4; ii++)
#pragma unroll
      for (int jj = 0; jj < 4; jj++) acc[ii][jj] = fmaf(av[ii], wv[jj], acc[ii][jj]);
  }
  float bl[4];
#pragma unroll
  for (int jj = 0; jj < 4; jj++) bl[jj] = b2[j * 4 + jj];
#pragma unroll
  for (int ii = 0; ii < 4; ii++) {
    union { ushort4 u4; __hip_bfloat16 h[4]; } pk;
#pragma unroll
    for (int jj = 0; jj < 4; jj++) {
      float y = acc[ii][jj] + bl[jj];
      acc[ii][jj] = y;
      pk.h[jj] = __float2bfloat16(y);
    }
    *(ushort4*)&Y[((size_t)(pbase + i * 4 + ii)) * 64 + j * 4] = pk.u4;
  }
#pragma unroll
  for (int jj = 0; jj < 4; jj++) {
    float s = 0.f, q2 = 0.f;
#pragma unroll
    for (int ii = 0; ii < 4; ii++) { float v = acc[ii][jj]; s += v; q2 += v * v; }
    atomicAdd(&ssum[j * 4 + jj], s);
    atomicAdd(&ssq[j * 4 + jj], q2);
  }
  __syncthreads();
  float* bb = bkt + (size_t)(blk & 63) * 512;
  if (t < 64) atomicAdd(&bb[128 + t], ssum[t]);
  else if (t < 128) atomicAdd(&bb[192 + (t - 64)], ssq[t - 64]);
}

// ---------------------------------------------------------------------------
// conv3max: bn2+relu(Y) -> conv3(64->128)+bias = y3; stats3 buckets AND
// per-(group,ch) max/min of y3 (BN3 affine is monotone; finalize picks).
// ---------------------------------------------------------------------------
__global__ __launch_bounds__(256) void conv3max_kernel(const u16* __restrict__ Y,
                                                       const float* __restrict__ w3,
                                                       const float* __restrict__ b3,
                                                       const float* __restrict__ g2,
                                                       const float* __restrict__ be2,
                                                       const float* __restrict__ statsC,
                                                       float* __restrict__ bkt,
                                                       float* __restrict__ gmax,
                                                       float* __restrict__ gmin) {
  __shared__ __align__(16) float As[64 * 64];
  __shared__ __align__(16) float Ws[64 * 128];
  __shared__ float sS[64], sT[64];
  __shared__ float ssum[128], ssq[128];
  const int t = threadIdx.x, blk = blockIdx.x;
  const int pbase = blk * 64;
  if (t < 64) {
    float mean = statsC[128 + t] * (1.0f / NT_F);
    float var = statsC[192 + t] * (1.0f / NT_F) - mean * mean;
    float s = g2[t] * rsqrtf(var + EPSV);
    sS[t] = s;
    sT[t] = be2[t] - mean * s;
  }
  if (t < 128) { ssum[t] = 0.f; ssq[t] = 0.f; }
  stage_W(w3, Ws, 64, 128, t);
  __syncthreads();
  stage_A_bn(Y, pbase, t, As, sS, sT);
  __syncthreads();
  const int i = t & 15, j = t >> 4, ob = j * 8;
  float acc[4][8];
#pragma unroll
  for (int a = 0; a < 4; a++)
#pragma unroll
    for (int c2 = 0; c2 < 8; c2++) acc[a][c2] = 0.f;
#pragma unroll 4
  for (int c = 0; c < 64; c++) {
    float4 a4 = *(const float4*)&As[c * 64 + i * 4];
    float4 w0 = *(const float4*)&Ws[c * 128 + ob];
    float4 w1v = *(const float4*)&Ws[c * 128 + ob + 4];
    float av[4] = {a4.x, a4.y, a4.z, a4.w};
    float wv[8] = {w0.x, w0.y, w0.z, w0.w, w1v.x, w1v.y, w1v.z, w1v.w};
#pragma unroll
    for (int ii = 0; ii < 4; ii++)
#pragma unroll
      for (int jj = 0; jj < 8; jj++) acc[ii][jj] = fmaf(av[ii], wv[jj], acc[ii][jj]);
  }
  float m[8], mn[8];
#pragma unroll
  for (int jj = 0; jj < 8; jj++) {
    float bl = b3[ob + jj];
    float v0 = acc[0][jj] + bl, v1 = acc[1][jj] + bl;
    float v2 = acc[2][jj] + bl, v3 = acc[3][jj] + bl;
    atomicAdd(&ssum[ob + jj], (v0 + v1) + (v2 + v3));
    atomicAdd(&ssq[ob + jj], (v0 * v0 + v1 * v1) + (v2 * v2 + v3 * v3));
    m[jj] = fmaxf(fmaxf(v0, v1), fmaxf(v2, v3));
    mn[jj] = fminf(fminf(v0, v1), fminf(v2, v3));
  }
#pragma unroll
  for (int off = 1; off < 8; off <<= 1)
#pragma unroll
    for (int jj = 0; jj < 8; jj++) {
      m[jj] = fmaxf(m[jj], __shfl_xor(m[jj], off));
      mn[jj] = fminf(mn[jj], __shfl_xor(mn[jj], off));
    }
  if ((i & 7) == 0) {
    int gidx = blk * 2 + (i >> 3);
#pragma unroll
    for (int jj = 0; jj < 8; jj++) {
      gmax[(size_t)gidx * 128 + ob + jj] = m[jj];
      gmin[(size_t)gidx * 128 + ob + jj] = mn[jj];
    }
  }
  __syncthreads();
  float* bb = bkt + (size_t)(blk & 63) * 512;
  if (t < 128) atomicAdd(&bb[256 + t], ssum[t]);
  else atomicAdd(&bb[384 + (t - 128)], ssq[t - 128]);
}

// ---------------------------------------------------------------------------
// finalize: out[b][o][s] = relu( sel * s3 + t3 ), sel = (s3>0 ? gmax : gmin)
// ---------------------------------------------------------------------------
__global__ __launch_bounds__(256) void finalize_kernel(const float* __restrict__ gmax,
                                                       const float* __restrict__ gmin,
                                                       const float* __restrict__ statsC,
                                                       const float* __restrict__ g3,
                                                       const float* __restrict__ be3,
                                                       float* __restrict__ outf) {
  int gi = blockIdx.x * 256 + threadIdx.x;  // 16*128*1024
  int s = gi & 1023;
  int o = (gi >> 10) & 127;
  int b = gi >> 17;
  float mean = statsC[256 + o] * (1.0f / NT_F);
  float var = statsC[384 + o] * (1.0f / NT_F) - mean * mean;
  float sc = g3[o] * rsqrtf(var + EPSV);
  float sh = be3[o] - mean * sc;
  size_t gidx = (size_t)(b * 1024 + s) * 128 + o;
  float v = sc > 0.f ? gmax[gidx] : gmin[gidx];
  outf[gi] = fmaxf(fmaf(v, sc, sh), 0.f);
}

// ---------------------------------------------------------------------------
// launch
// ---------------------------------------------------------------------------
extern "C" void kernel_launch(void* const* d_in, const int* in_sizes, int n_in,
                              void* d_out, int out_size, void* d_ws, size_t ws_size,
                              hipStream_t stream) {
  const float* xyz = (const float*)d_in[0];
  const float* pts = (const float*)d_in[1];
  const float* w1 = (const float*)d_in[2];
  const float* b1 = (const float*)d_in[3];
  const float* g1 = (const float*)d_in[4];
  const float* be1 = (const float*)d_in[5];
  const float* w2 = (const float*)d_in[6];
  const float* b2 = (const float*)d_in[7];
  const float* g2 = (const float*)d_in[8];
  const float* be2 = (const float*)d_in[9];
  const float* w3 = (const float*)d_in[10];
  const float* b3 = (const float*)d_in[11];
  const float* g3 = (const float*)d_in[12];
  const float* be3 = (const float*)d_in[13];

  float* out = (float*)d_out;
  float* newxyz = out;            // 16*1024*3
  float* outfeat = out + 49152;   // 16*128*1024

  char* ws = (char*)d_ws;
  int* ballidx = (int*)ws;                          // 2 MB
  float* bkt = (float*)(ws + (2 << 20));            // 64*512*4 = 128 KB
  float* statsC = (float*)(ws + (2 << 20) + 131072);// 2 KB
  float* gmax = (float*)(ws + (4 << 20));           // 8 MB
  float* gmin = (float*)(ws + (12 << 20));          // 8 MB
  u16* Y = (u16*)(ws + (20 << 20));                 // 64 MiB (in-place Y1->Y2)

  hipMemsetAsync(bkt, 0, 64 * 512 * sizeof(float), stream);

  // FPS: prefer 96KB-LDS coord-cache variant; fall back to global-fetch.
  bool use_lds = false;
  {
    hipError_t e = hipFuncSetAttribute((const void*)fps_kernel_t<1>,
                                       hipFuncAttributeMaxDynamicSharedMemorySize, 98304);
    if (e == hipSuccess) {
      int nb = 0;
      hipError_t e2 = hipOccupancyMaxActiveBlocksPerMultiprocessor(
          &nb, (const void*)fps_kernel_t<1>, 512, 98304);
      use_lds = (e2 == hipSuccess && nb >= 1);
    }
  }
  if (use_lds)
    fps_kernel_t<1><<<16, 512, 98304, stream>>>(xyz, newxyz);
  else
    fps_kernel_t<0><<<16, 512, 0, stream>>>(xyz, newxyz);

  ballq_kernel<<<4096, 256, 0, stream>>>(xyz, newxyz, ballidx);
  gemm1_kernel<<<8192, 256, 0, stream>>>(xyz, pts, w1, b1, newxyz, ballidx, Y, bkt);
  collapse_kernel<<<2, 256, 0, stream>>>(bkt, statsC);
  gemm2_kernel<<<8192, 256, 0, stream>>>(Y, w2, b2, g1, be1, statsC, bkt);
  collapse_kernel<<<2, 256, 0, stream>>>(bkt, statsC);
  conv3max_kernel<<<8192, 256, 0, stream>>>(Y, w3, b3, g2, be2, statsC, bkt, gmax, gmin);
  collapse_kernel<<<2, 256, 0, stream>>>(bkt, statsC);
  finalize_kernel<<<8192, 256, 0, stream>>>(gmax, gmin, statsC, g3, be3, outfeat);
}